// Round 5
// baseline (293.027 us; speedup 1.0000x reference)
//
#include <hip/hip_runtime.h>
#include <hip/hip_bf16.h>
#include <stdint.h>

typedef __attribute__((ext_vector_type(8))) short short8;
typedef __attribute__((ext_vector_type(8))) unsigned short ushort8;
typedef __attribute__((ext_vector_type(4))) float f32x4;
typedef unsigned short ushort_t;

// ---------------- fused conversion kernel (memory-bound) ----------------
// region 0: x fp32 -> bf16 RNE.  region 1: W fp32 -> sign(W) in bf16 {-1,0,+1}.

__device__ __forceinline__ unsigned short f2bf_rne(float f) {
    union { float f; unsigned int u; } v; v.f = f;
    unsigned int u = v.u;
    unsigned int r = u + 0x7FFFu + ((u >> 16) & 1u);
    return (unsigned short)(r >> 16);
}

__device__ __forceinline__ unsigned short signbf(float f) {
    return (f > 0.0f) ? (unsigned short)0x3F80u
         : (f < 0.0f) ? (unsigned short)0xBF80u
                      : (unsigned short)0u;
}

__global__ __launch_bounds__(256) void cvt_fused(
    const float* __restrict__ x, const float* __restrict__ W,
    ushort_t* __restrict__ xb, ushort_t* __restrict__ wb,
    int n8x, int n8total)
{
    const int stride = gridDim.x * 256;
    for (int i = blockIdx.x * 256 + threadIdx.x; i < n8total; i += stride) {
        const bool isx = i < n8x;
        const float* src = isx ? x : W;
        ushort_t* dst    = isx ? xb : wb;
        const int j      = isx ? i : i - n8x;
        const float4* p = reinterpret_cast<const float4*>(src) + (size_t)j * 2;
        float4 a = p[0];
        float4 b = p[1];
        ushort8 o;
        if (isx) {
            o[0] = f2bf_rne(a.x); o[1] = f2bf_rne(a.y); o[2] = f2bf_rne(a.z); o[3] = f2bf_rne(a.w);
            o[4] = f2bf_rne(b.x); o[5] = f2bf_rne(b.y); o[6] = f2bf_rne(b.z); o[7] = f2bf_rne(b.w);
        } else {
            o[0] = signbf(a.x); o[1] = signbf(a.y); o[2] = signbf(a.z); o[3] = signbf(a.w);
            o[4] = signbf(b.x); o[5] = signbf(b.y); o[6] = signbf(b.z); o[7] = signbf(b.w);
        }
        *reinterpret_cast<ushort8*>(dst + (size_t)j * 8) = o;
    }
}

// ---------------- 256x256 8-wave phase-split bf16 GEMM: C = A @ B^T + bias ---
// A: [M][K] bf16 (x).  B: [N][K] bf16 (sign(W)).  C: [M][N] fp32.
// Identical to the round-2 PASSED kernel except:
//  - tile-end __syncthreads -> s_waitcnt vmcnt(2) + s_barrier
//  - phase-1 trailing barrier -> s_waitcnt vmcnt(8) + s_barrier
//  - last tile wrap-stages k=0 (uniform ledger, no guard)
// Ledger (per wave, burst of 8 gloads/tile, order A00,A10,B00,B10,B01,B11,
// A01,A11): carry-in = {A01,A11} of CURRENT tile; vmcnt(8) at ph1-end drains
// them just before ph2 reads those rows; vmcnt(2) at tile-end drains the 6
// chunks next ph0/ph1 read, leaving the new {A01,A11} in flight. Never 0.

#define BM 256
#define BN 256
#define BK 64

__device__ __forceinline__ void gload_lds16(const void* g, void* l) {
    __builtin_amdgcn_global_load_lds(
        (const __attribute__((address_space(1))) unsigned int*)g,
        (__attribute__((address_space(3))) unsigned int*)l,
        16, 0, 0);
}

__device__ __forceinline__ void phase_barrier() {
    __builtin_amdgcn_sched_barrier(0);
    __builtin_amdgcn_s_barrier();
    __builtin_amdgcn_sched_barrier(0);
}

__device__ __forceinline__ void bar_vm8() {
    __builtin_amdgcn_sched_barrier(0);
    asm volatile("s_waitcnt vmcnt(8)" ::: "memory");
    __builtin_amdgcn_s_barrier();
    __builtin_amdgcn_sched_barrier(0);
}

__device__ __forceinline__ void bar_vm2() {
    __builtin_amdgcn_sched_barrier(0);
    asm volatile("s_waitcnt vmcnt(2)" ::: "memory");
    __builtin_amdgcn_s_barrier();
    __builtin_amdgcn_sched_barrier(0);
}

// stage one 256x64 K-tile of A and B (8 chunks, 1 gload per wave per chunk).
// order matters for the vmcnt ledger: A01,A11 must be the LAST two issued.
__device__ __forceinline__ void stage_tile(
    const ushort_t* __restrict__ A, const ushort_t* __restrict__ B,
    ushort_t* ldsA, ushort_t* ldsB,
    int brow, int bcol, int kbase, int K,
    int wid, int srow, int scol)
{
    const int ro0 = wid * 8;
    // A00 (rows 0-63), A10 (128-191)
    gload_lds16(A + (size_t)(brow + 0   + ro0 + srow) * K + kbase + scol, ldsA + (0   + ro0) * 64);
    gload_lds16(A + (size_t)(brow + 128 + ro0 + srow) * K + kbase + scol, ldsA + (128 + ro0) * 64);
    // B00, B10, B01, B11
    gload_lds16(B + (size_t)(bcol + 0   + ro0 + srow) * K + kbase + scol, ldsB + (0   + ro0) * 64);
    gload_lds16(B + (size_t)(bcol + 128 + ro0 + srow) * K + kbase + scol, ldsB + (128 + ro0) * 64);
    gload_lds16(B + (size_t)(bcol + 64  + ro0 + srow) * K + kbase + scol, ldsB + (64  + ro0) * 64);
    gload_lds16(B + (size_t)(bcol + 192 + ro0 + srow) * K + kbase + scol, ldsB + (192 + ro0) * 64);
    // A01 (rows 64-127), A11 (192-255) — last two issued
    gload_lds16(A + (size_t)(brow + 64  + ro0 + srow) * K + kbase + scol, ldsA + (64  + ro0) * 64);
    gload_lds16(A + (size_t)(brow + 192 + ro0 + srow) * K + kbase + scol, ldsA + (192 + ro0) * 64);
}

__global__ __launch_bounds__(512, 2) void gemm8_bt_bias(
    const ushort_t* __restrict__ A,
    const ushort_t* __restrict__ B,
    const float* __restrict__ bias,
    float* __restrict__ C,
    int M, int N, int K, int tn_n)
{
    extern __shared__ ushort_t lds[];
    // A buf b: lds[b*16384 + row*64 + col]; B buf b: lds[32768 + b*16384 + ...]

    const int tid  = threadIdx.x;
    const int wid  = tid >> 6;
    const int lane = tid & 63;
    const int wr = wid >> 2;       // 0..1 (M)
    const int wc = wid & 3;        // 0..3 (N)

    // XCD-aware bijective swizzle (m204)
    unsigned nwg = gridDim.x, orig = blockIdx.x;
    unsigned qd = nwg >> 3, rm = nwg & 7u;
    unsigned xcd = orig & 7u, sub = orig >> 3;
    unsigned id = (xcd < rm ? xcd * (qd + 1) : rm * (qd + 1) + (xcd - rm) * qd) + sub;
    const int tm = (int)(id / (unsigned)tn_n);
    const int tn = (int)(id % (unsigned)tn_n);
    const int brow = tm * BM;
    const int bcol = tn * BN;

    const int nt = K / BK;

    // staging per-lane constants (T2 inverse swizzle on global source)
    const int srow = lane >> 3;                       // 0..7
    const int scol = ((lane & 7) ^ srow) << 3;        // bf16 col offset

    // frag-read per-lane constants (swizzled ds_read)
    const int r15 = lane & 15;
    const int hi2 = lane >> 4;                        // 0..3
    const int l7  = lane & 7;
    const int sK0 = ((hi2) ^ l7) * 8;                 // kk=0 slot
    const int sK1 = ((4 + hi2) ^ l7) * 8;             // kk=1 slot
    const int bRow = (wc & 1) * 64;

    f32x4 acc[8][4];
#pragma unroll
    for (int m = 0; m < 8; ++m)
#pragma unroll
        for (int n = 0; n < 4; ++n)
            acc[m][n] = (f32x4){0.f, 0.f, 0.f, 0.f};

    // prologue: stage tile 0 into buf 0; drain all but the final {A01,A11}
    stage_tile(A, B, lds, lds + 32768, brow, bcol, 0, K, wid, srow, scol);
    bar_vm2();

    short8 aF[2][4], bF[2][4];

    for (int t = 0; t < nt; ++t) {
        const int cur = t & 1;
        const int nxt = cur ^ 1;
        const ushort_t* aC = lds + cur * 16384 + wr * 8192;
        const ushort_t* bC = lds + 32768 + cur * 16384 + (wc >> 1) * 8192;
        const int kn = (t == nt - 1) ? 0 : (t + 1) * BK;  // wrap: harmless reload

        // issue next tile's staging burst (in flight across all 4 phases)
        stage_tile(A, B, lds + nxt * 16384, lds + 32768 + nxt * 16384,
                   brow, bcol, kn, K, wid, srow, scol);

        // ---- phase 0: read A m0-3 + B n0-1; MFMA q0 ----
#pragma unroll
        for (int i = 0; i < 4; ++i) {
            aF[0][i] = *reinterpret_cast<const short8*>(aC + (i * 16 + r15) * 64 + sK0);
            aF[1][i] = *reinterpret_cast<const short8*>(aC + (i * 16 + r15) * 64 + sK1);
        }
#pragma unroll
        for (int n = 0; n < 2; ++n) {
            bF[0][n] = *reinterpret_cast<const short8*>(bC + (bRow + n * 16 + r15) * 64 + sK0);
            bF[1][n] = *reinterpret_cast<const short8*>(bC + (bRow + n * 16 + r15) * 64 + sK1);
        }
        phase_barrier();
        __builtin_amdgcn_s_setprio(1);
#pragma unroll
        for (int i = 0; i < 4; ++i)
#pragma unroll
            for (int j = 0; j < 2; ++j) {
                f32x4 c = acc[i][j];
                c = __builtin_amdgcn_mfma_f32_16x16x32_bf16(aF[0][i], bF[0][j], c, 0, 0, 0);
                c = __builtin_amdgcn_mfma_f32_16x16x32_bf16(aF[1][i], bF[1][j], c, 0, 0, 0);
                acc[i][j] = c;
            }
        __builtin_amdgcn_s_setprio(0);
        phase_barrier();

        // ---- phase 1: read B n2-3; MFMA q1 ----
#pragma unroll
        for (int n = 2; n < 4; ++n) {
            bF[0][n] = *reinterpret_cast<const short8*>(bC + (bRow + n * 16 + r15) * 64 + sK0);
            bF[1][n] = *reinterpret_cast<const short8*>(bC + (bRow + n * 16 + r15) * 64 + sK1);
        }
        phase_barrier();
        __builtin_amdgcn_s_setprio(1);
#pragma unroll
        for (int i = 0; i < 4; ++i)
#pragma unroll
            for (int j = 2; j < 4; ++j) {
                f32x4 c = acc[i][j];
                c = __builtin_amdgcn_mfma_f32_16x16x32_bf16(aF[0][i], bF[0][j], c, 0, 0, 0);
                c = __builtin_amdgcn_mfma_f32_16x16x32_bf16(aF[1][i], bF[1][j], c, 0, 0, 0);
                acc[i][j] = c;
            }
        __builtin_amdgcn_s_setprio(0);
        bar_vm8();   // drain THIS tile's {A01,A11} (carry-in) before ph2 reads

        // ---- phase 2: read A m4-7; MFMA q2 ----
#pragma unroll
        for (int i = 0; i < 4; ++i) {
            aF[0][i] = *reinterpret_cast<const short8*>(aC + ((4 + i) * 16 + r15) * 64 + sK0);
            aF[1][i] = *reinterpret_cast<const short8*>(aC + ((4 + i) * 16 + r15) * 64 + sK1);
        }
        phase_barrier();
        __builtin_amdgcn_s_setprio(1);
#pragma unroll
        for (int i = 0; i < 4; ++i)
#pragma unroll
            for (int j = 0; j < 2; ++j) {
                f32x4 c = acc[4 + i][j];
                c = __builtin_amdgcn_mfma_f32_16x16x32_bf16(aF[0][i], bF[0][j], c, 0, 0, 0);
                c = __builtin_amdgcn_mfma_f32_16x16x32_bf16(aF[1][i], bF[1][j], c, 0, 0, 0);
                acc[4 + i][j] = c;
            }
        __builtin_amdgcn_s_setprio(0);
        phase_barrier();

        // ---- phase 3: MFMA q3 (no new reads) ----
        __builtin_amdgcn_s_setprio(1);
#pragma unroll
        for (int i = 0; i < 4; ++i)
#pragma unroll
            for (int j = 2; j < 4; ++j) {
                f32x4 c = acc[4 + i][j];
                c = __builtin_amdgcn_mfma_f32_16x16x32_bf16(aF[0][i], bF[0][j], c, 0, 0, 0);
                c = __builtin_amdgcn_mfma_f32_16x16x32_bf16(aF[1][i], bF[1][j], c, 0, 0, 0);
                acc[4 + i][j] = c;
            }
        __builtin_amdgcn_s_setprio(0);

        // tile end: drain next tile's 6 early chunks; leave its {A01,A11} flying
        bar_vm2();
    }

    // epilogue: C[row][col] = acc + bias[col]
    // C/D layout (m89/m91): col = lane&15, row = (lane>>4)*4 + j
#pragma unroll
    for (int n = 0; n < 4; ++n) {
        const int col = bcol + wc * 64 + n * 16 + r15;
        const float bv = bias[col];
#pragma unroll
        for (int m = 0; m < 8; ++m) {
            const int row0 = brow + wr * 128 + m * 16 + hi2 * 4;
#pragma unroll
            for (int j = 0; j < 4; ++j) {
                C[(size_t)(row0 + j) * N + col] = acc[m][n][j] + bv;
            }
        }
    }
}

// ---------------- launcher ----------------

extern "C" void kernel_launch(void* const* d_in, const int* in_sizes, int n_in,
                              void* d_out, int out_size, void* d_ws, size_t ws_size,
                              hipStream_t stream) {
    const float* x  = (const float*)d_in[0];
    const float* W  = (const float*)d_in[1];
    const float* bv = (const float*)d_in[2];
    float* out = (float*)d_out;

    const int OUT = in_sizes[2];                 // 4096
    const int IN  = in_sizes[1] / OUT;           // 4096
    const int M   = in_sizes[0] / IN;            // 4096

    unsigned short* xb = (unsigned short*)d_ws;              // [M][IN] bf16
    unsigned short* wb = xb + (size_t)M * IN;                // [OUT][IN] bf16

    const int n8x = (M * IN) / 8;
    const int n8w = (OUT * IN) / 8;
    cvt_fused<<<2048, 256, 0, stream>>>(x, W, xb, wb, n8x, n8x + n8w);

    const int tn_n = OUT / BN;
    const int tm_n = M / BM;
    const int nblk = tn_n * tm_n;
    (void)hipFuncSetAttribute((const void*)gemm8_bt_bias,
                              hipFuncAttributeMaxDynamicSharedMemorySize, 131072);
    gemm8_bt_bias<<<nblk, 512, 131072, stream>>>(xb, wb, bv, out, M, OUT, IN, tn_n);
}